// Round 1
// 360.031 us; speedup vs baseline: 1.0351x; 1.0351x over previous
//
#include <hip/hip_runtime.h>

#define T_DIM 512
#define C_DIM 48
#define BPS   64          // bp row stride (padded to 64 so all lanes store)
#define CH    4           // global-prefetch chunk (distance ~4-8 steps)

typedef float f32x2 __attribute__((ext_vector_type(2)));
typedef float f32x4 __attribute__((ext_vector_type(4)));

#if __has_builtin(__builtin_amdgcn_readlane)
#define READLANE_I(v, l) __builtin_amdgcn_readlane((v), (l))
#else
#define READLANE_I(v, l) __shfl((v), (l), 64)
#endif

// Compiler-level ordering fence for single-wave LDS communication.
// DS ops from one wave execute in order; we only need to stop the compiler
// from reordering/caching across the phase boundary. (Validated R3: absmax=0.)
#if __has_builtin(__builtin_amdgcn_wave_barrier)
#define WAVE_SYNC() do { __asm__ __volatile__("" ::: "memory"); __builtin_amdgcn_wave_barrier(); } while (0)
#else
#define WAVE_SYNC() __asm__ __volatile__("" ::: "memory")
#endif

__device__ __forceinline__ unsigned umin_(unsigned a, unsigned b) { return a < b ? a : b; }

#define MAX3(a, b, c) fmaxf(fmaxf((a), (b)), (c))
#define CV(I_)  (cv2[(I_) / 2][(I_) & 1])
// d = cv_i - m is +0.0 (bits 0) iff cv_i == m, else negative (bits >= 0x80000000).
// bits(d)|i == i for max-tier, huge otherwise; umin -> lowest max-tier index
// == jnp.argmax first-occurrence tie-break, exactly. (Validated R8: absmax=0.)
#define UU(I_)  (__float_as_uint(d2[(I_) / 2][(I_) & 1]) | (unsigned)(I_))
#define EMIN3(I_) umin_(umin_(UU(I_), UU((I_) + 1)), UU((I_) + 2))

// One Viterbi step, register-only broadcast version.
// Previous step left the per-column score in `ns` (lane j holds column j).
// Broadcast all 48 scores to wave-uniform SGPRs via v_readlane (no LDS on
// the critical path), then lane j computes argmax_i(s_i + tc_i[j]).
// Adds are scalar v_add_f32 (SGPR + VGPR) -- elementwise identical fp ops
// to the previous packed version, so results stay bit-exact.
#define VSTEP(T_, PV_) do {                                                  \
    const int nsi_ = __float_as_int(ns);                                     \
    float su_[C_DIM];                                                        \
    _Pragma("unroll")                                                        \
    for (int k_ = 0; k_ < C_DIM; ++k_)                                       \
        su_[k_] = __int_as_float(READLANE_I(nsi_, k_));                      \
    f32x2 cv2[24];                                                           \
    _Pragma("unroll")                                                        \
    for (int m_ = 0; m_ < 24; ++m_) {                                        \
        cv2[m_][0] = su_[2 * m_]     + tc2[m_][0];                           \
        cv2[m_][1] = su_[2 * m_ + 1] + tc2[m_][1];                           \
    }                                                                        \
    float A0  = MAX3(CV(0),  CV(1),  CV(2));                                 \
    float A1  = MAX3(CV(3),  CV(4),  CV(5));                                 \
    float A2  = MAX3(CV(6),  CV(7),  CV(8));                                 \
    float A3  = MAX3(CV(9),  CV(10), CV(11));                                \
    float A4  = MAX3(CV(12), CV(13), CV(14));                                \
    float A5  = MAX3(CV(15), CV(16), CV(17));                                \
    float A6  = MAX3(CV(18), CV(19), CV(20));                                \
    float A7  = MAX3(CV(21), CV(22), CV(23));                                \
    float A8  = MAX3(CV(24), CV(25), CV(26));                                \
    float A9  = MAX3(CV(27), CV(28), CV(29));                                \
    float A10 = MAX3(CV(30), CV(31), CV(32));                                \
    float A11 = MAX3(CV(33), CV(34), CV(35));                                \
    float A12 = MAX3(CV(36), CV(37), CV(38));                                \
    float A13 = MAX3(CV(39), CV(40), CV(41));                                \
    float A14 = MAX3(CV(42), CV(43), CV(44));                                \
    float A15 = MAX3(CV(45), CV(46), CV(47));                                \
    float B0 = MAX3(A0,  A1,  A2);                                           \
    float B1 = MAX3(A3,  A4,  A5);                                           \
    float B2 = MAX3(A6,  A7,  A8);                                           \
    float B3 = MAX3(A9,  A10, A11);                                          \
    float B4 = MAX3(A12, A13, A14);                                          \
    float Cx0 = MAX3(B0, B1, B2);                                            \
    float Cx1 = MAX3(B3, B4, A15);                                           \
    const float m_v = fmaxf(Cx0, Cx1);                                       \
    f32x2 d2[24];                                                            \
    _Pragma("unroll")                                                        \
    for (int k_ = 0; k_ < 24; ++k_) d2[k_] = cv2[k_] - m_v;  /* pk sub */    \
    unsigned U0  = EMIN3(0);   unsigned U1  = EMIN3(3);                      \
    unsigned U2  = EMIN3(6);   unsigned U3  = EMIN3(9);                      \
    unsigned U4  = EMIN3(12);  unsigned U5  = EMIN3(15);                     \
    unsigned U6  = EMIN3(18);  unsigned U7  = EMIN3(21);                     \
    unsigned U8  = EMIN3(24);  unsigned U9  = EMIN3(27);                     \
    unsigned U10 = EMIN3(30);  unsigned U11 = EMIN3(33);                     \
    unsigned U12 = EMIN3(36);  unsigned U13 = EMIN3(39);                     \
    unsigned U14 = EMIN3(42);  unsigned U15 = EMIN3(45);                     \
    unsigned V0 = umin_(umin_(U0,  U1),  U2);                                \
    unsigned V1 = umin_(umin_(U3,  U4),  U5);                                \
    unsigned V2 = umin_(umin_(U6,  U7),  U8);                                \
    unsigned V3 = umin_(umin_(U9,  U10), U11);                               \
    unsigned V4 = umin_(umin_(U12, U13), U14);                               \
    unsigned W0 = umin_(umin_(V0, V1), V2);                                  \
    unsigned W1 = umin_(umin_(V3, V4), U15);                                 \
    const unsigned wi_ = umin_(W0, W1);                                      \
    ns = m_v + (PV_);                                                        \
    bp[(T_) * BPS + tid] = (unsigned char)wi_;  /* all 64 lanes; pad ok */   \
} while (0)

__global__ __launch_bounds__(64) void crf_viterbi(
    const float* __restrict__ pot,     // [B][T][C]
    const int*   __restrict__ seqlen,  // [B][1]
    const float* __restrict__ trans,   // [C][C]
    float*       __restrict__ out)     // [B][T][C] one-hot f32
{
    const int b   = blockIdx.x;
    const int tid = threadIdx.x;
    const int jj  = (tid < C_DIM) ? tid : (C_DIM - 1);  // clamped for safe loads

    __shared__ unsigned char bp[T_DIM * BPS];            // rows 1..L-1 used
    __shared__ __align__(4) unsigned char tags[T_DIM];
    __shared__ __align__(16) float fsc[64];              // final scores (phase 2)

    const float* potb = pot + (size_t)b * (T_DIM * C_DIM);
    const int L   = seqlen[b];          // in [1, 511]
    const int thi = L - 1;

    // transitions column j as 24 packed pairs (clamped col for lanes >= 48)
    f32x2 tc2[24];
#pragma unroll
    for (int k = 0; k < 24; ++k) {
        tc2[k][0] = trans[(2 * k)     * C_DIM + jj];
        tc2[k][1] = trans[(2 * k + 1) * C_DIM + jj];
    }

    // init: lane j holds score[j] = potentials[b, 0, j] in a register
    float ns = potb[jj];

    const float* pp = potb + jj;

    // software-pipelined forward loop: prefetch chunk CH ahead (clamped rows)
    float pb[CH];
#pragma unroll
    for (int k = 0; k < CH; ++k) {
        int tt = 1 + k; if (tt > T_DIM - 1) tt = T_DIM - 1;
        pb[k] = pp[tt * C_DIM];
    }
    for (int t0 = 1; t0 < L; t0 += CH) {
        float nb[CH];
#pragma unroll
        for (int k = 0; k < CH; ++k) {
            int tt = t0 + CH + k; if (tt > T_DIM - 1) tt = T_DIM - 1;
            nb[k] = pp[tt * C_DIM];
        }
#pragma unroll
        for (int k = 0; k < CH; ++k) {
            const int t = t0 + k;
            if (t >= L) break;           // wave-uniform branch
            VSTEP(t, pb[k]);
        }
#pragma unroll
        for (int k = 0; k < CH; ++k) pb[k] = nb[k];
    }

    // publish final scores for the argmax (single LDS round trip, off the
    // recurrence critical path)
    fsc[tid] = ns;
    WAVE_SYNC();
    __syncthreads();   // phase boundary (single wave; cheap)

    // last_tag = argmax over final scores (uniform LDS reads, broadcast)
    const float* fs = fsc;
    float bv = fs[0];
    int   bi = 0;
#pragma unroll
    for (int i = 1; i < C_DIM; ++i) {
        float v = fs[i];
        if (v > bv) { bv = v; bi = i; }
    }
    const int last_tag = __builtin_amdgcn_readfirstlane(bi);

    // prefill tags[t] = last_tag for t in [L, T)
    for (int t = L + tid; t < T_DIM; t += 64) tags[t] = (unsigned char)last_tag;

    // serial backtrace: for t = thi..1: tags[t] = y; y = bp[t][y];  then tags[0] = y
    int y = last_tag;  // wave-uniform
    for (int c0 = (thi >> 6) << 6; c0 >= 0; c0 -= 64) {
        int row[64];   // row[k] holds bp[c0+k][jj] in lane jj
#pragma unroll
        for (int k = 0; k < 64; ++k) row[k] = bp[(c0 + k) * BPS + jj];

        int vacc = 0;
#pragma unroll
        for (int k = 63; k >= 0; --k) {
            const int t = c0 + k;
            vacc = (tid == k) ? y : vacc;                        // tags[t] = y (lane k)
            const int ynew = READLANE_I(row[k], y);
            if ((unsigned)(t - 1) < (unsigned)thi) y = ynew;     // update only for t in [1, thi]
        }
        const int tk = c0 + tid;
        if (tk <= thi) tags[tk] = (unsigned char)(vacc & 0xff);
    }
    __syncthreads();   // phase boundary

    // emit one-hot: 4 rows (t) per iteration, 48 lanes x float4 = 768B coalesced
    if (tid < C_DIM) {
        const int r = tid / 12;          // row-in-group 0..3
        const int q = tid - r * 12;      // float4 slot 0..11
        const int cbase = q * 4;
        float* ob = out + (size_t)b * (T_DIM * C_DIM);
        for (int t0 = 0; t0 < T_DIM; t0 += 4) {
            const unsigned int tg4 = *(const unsigned int*)&tags[t0];
            const int mytag = (int)((tg4 >> (r * 8)) & 0xffu);
            float4 v;
            v.x = (cbase + 0 == mytag) ? 1.0f : 0.0f;
            v.y = (cbase + 1 == mytag) ? 1.0f : 0.0f;
            v.z = (cbase + 2 == mytag) ? 1.0f : 0.0f;
            v.w = (cbase + 3 == mytag) ? 1.0f : 0.0f;
            *(float4*)(ob + (size_t)(t0 + r) * C_DIM + cbase) = v;
        }
    }
}

extern "C" void kernel_launch(void* const* d_in, const int* in_sizes, int n_in,
                              void* d_out, int out_size, void* d_ws, size_t ws_size,
                              hipStream_t stream) {
    const float* pot    = (const float*)d_in[0];
    const int*   sl     = (const int*)d_in[1];
    const float* trans  = (const float*)d_in[2];
    float*       out    = (float*)d_out;
    const int B = in_sizes[1];  // sequence_lengths has B elements
    crf_viterbi<<<B, 64, 0, stream>>>(pot, sl, trans, out);
}

// Round 3
// 345.009 us; speedup vs baseline: 1.0801x; 1.0435x over previous
//
#include <hip/hip_runtime.h>

#define T_DIM 512
#define C_DIM 48
#define BPS   64          // bp row stride (padded to 64 so all lanes store)
#define CH    4           // global-prefetch chunk (distance ~4-8 steps)

typedef float f32x2 __attribute__((ext_vector_type(2)));
typedef float f32x4 __attribute__((ext_vector_type(4)));

#if __has_builtin(__builtin_amdgcn_readlane)
#define READLANE_I(v, l) __builtin_amdgcn_readlane((v), (l))
#else
#define READLANE_I(v, l) __shfl((v), (l), 64)
#endif

// Compiler-level ordering fence for single-wave LDS communication.
// DS ops from one wave execute in order; we only need to stop the compiler
// from reordering/caching across the step boundary. (Validated R3: absmax=0.)
#if __has_builtin(__builtin_amdgcn_wave_barrier)
#define WAVE_SYNC() do { __asm__ __volatile__("" ::: "memory"); __builtin_amdgcn_wave_barrier(); } while (0)
#else
#define WAVE_SYNC() __asm__ __volatile__("" ::: "memory")
#endif

__device__ __forceinline__ unsigned umin_(unsigned a, unsigned b) { return a < b ? a : b; }

// Pin the 3-ary reductions to single instructions (fmaxf chains may not fuse
// to v_max3_f32 without fast-math). Exact for non-NaN data, same result as
// fmaxf(fmaxf(a,b),c) / umin(umin(a,b),c).
__device__ __forceinline__ float max3f(float a, float b, float c) {
    float d;
    asm("v_max3_f32 %0, %1, %2, %3" : "=v"(d) : "v"(a), "v"(b), "v"(c));
    return d;
}
__device__ __forceinline__ unsigned min3u(unsigned a, unsigned b, unsigned c) {
    unsigned d;
    asm("v_min3_u32 %0, %1, %2, %3" : "=v"(d) : "v"(a), "v"(b), "v"(c));
    return d;
}

#define CV(I_)  (cv2[(I_) / 2][(I_) & 1])
// d = cv_i - m is +0.0 (bits 0) iff cv_i == m, else negative (bits >= 0x80000000).
// bits(d)|i == i for max-tier, huge otherwise; umin -> lowest max-tier index
// == jnp.argmax first-occurrence tie-break, exactly. (Validated R8: absmax=0.)
#define UU(I_)  (__float_as_uint(d2[(I_) / 2][(I_) & 1]) | (unsigned)(I_))
#define EMIN3(I_) min3u(UU(I_), UU((I_) + 1), UU((I_) + 2))

// One Viterbi step, latency-hiding schedule.
// Entry state: cv2[24] holds this step's candidate scores (s_i + tc_i[j]).
// Order: value tree -> ns -> ds_write(sc) -> issue 12x ds_read_b128 of the
// NEW score vector -> argmax-extract + bp store (~190cy of VALU, hides the
// ds_read latency) -> packed adds produce cv2 for the next step.
// All fp ops element-wise identical to the validated version -> bit-exact.
#define VSTEP(T_, PV_) do {                                                  \
    float A0  = max3f(CV(0),  CV(1),  CV(2));                                \
    float A1  = max3f(CV(3),  CV(4),  CV(5));                                \
    float A2  = max3f(CV(6),  CV(7),  CV(8));                                \
    float A3  = max3f(CV(9),  CV(10), CV(11));                               \
    float A4  = max3f(CV(12), CV(13), CV(14));                               \
    float A5  = max3f(CV(15), CV(16), CV(17));                               \
    float A6  = max3f(CV(18), CV(19), CV(20));                               \
    float A7  = max3f(CV(21), CV(22), CV(23));                               \
    float A8  = max3f(CV(24), CV(25), CV(26));                               \
    float A9  = max3f(CV(27), CV(28), CV(29));                               \
    float A10 = max3f(CV(30), CV(31), CV(32));                               \
    float A11 = max3f(CV(33), CV(34), CV(35));                               \
    float A12 = max3f(CV(36), CV(37), CV(38));                               \
    float A13 = max3f(CV(39), CV(40), CV(41));                               \
    float A14 = max3f(CV(42), CV(43), CV(44));                               \
    float A15 = max3f(CV(45), CV(46), CV(47));                               \
    float B0 = max3f(A0,  A1,  A2);                                          \
    float B1 = max3f(A3,  A4,  A5);                                          \
    float B2 = max3f(A6,  A7,  A8);                                          \
    float B3 = max3f(A9,  A10, A11);                                         \
    float B4 = max3f(A12, A13, A14);                                         \
    float Cx0 = max3f(B0, B1, B2);                                           \
    float Cx1 = max3f(B3, B4, A15);                                          \
    const float m_v = fmaxf(Cx0, Cx1);                                       \
    const float ns_ = m_v + (PV_);                                           \
    const int nxt_ = cur ^ 1;                                                \
    sc[nxt_][tid] = ns_;                        /* lanes 48-63 hit pad */    \
    WAVE_SYNC();                                                             \
    const f32x4* sp_ = (const f32x4*)sc[nxt_];                               \
    f32x4 sv_[12];                                                           \
    _Pragma("unroll")                                                        \
    for (int m_ = 0; m_ < 12; ++m_) sv_[m_] = sp_[m_];  /* issue reads */    \
    /* argmax extract for step T_ -- independent of the reads above */       \
    f32x2 d2[24];                                                            \
    const f32x2 mv2_ = {m_v, m_v};                                           \
    _Pragma("unroll")                                                        \
    for (int k_ = 0; k_ < 24; ++k_) d2[k_] = cv2[k_] - mv2_;  /* pk sub */   \
    unsigned U0  = EMIN3(0);   unsigned U1  = EMIN3(3);                      \
    unsigned U2  = EMIN3(6);   unsigned U3  = EMIN3(9);                      \
    unsigned U4  = EMIN3(12);  unsigned U5  = EMIN3(15);                     \
    unsigned U6  = EMIN3(18);  unsigned U7  = EMIN3(21);                     \
    unsigned U8  = EMIN3(24);  unsigned U9  = EMIN3(27);                     \
    unsigned U10 = EMIN3(30);  unsigned U11 = EMIN3(33);                     \
    unsigned U12 = EMIN3(36);  unsigned U13 = EMIN3(39);                     \
    unsigned U14 = EMIN3(42);  unsigned U15 = EMIN3(45);                     \
    unsigned V0 = min3u(U0,  U1,  U2);                                       \
    unsigned V1 = min3u(U3,  U4,  U5);                                       \
    unsigned V2 = min3u(U6,  U7,  U8);                                       \
    unsigned V3 = min3u(U9,  U10, U11);                                      \
    unsigned V4 = min3u(U12, U13, U14);                                      \
    unsigned W0 = min3u(V0, V1, V2);                                         \
    unsigned W1 = min3u(V3, V4, U15);                                        \
    const unsigned wi_ = umin_(W0, W1);                                      \
    bp[(T_) * BPS + tid] = (unsigned char)wi_;  /* all 64 lanes; pad ok */   \
    /* packed adds for the next step (compiler inserts lgkmcnt waits) */     \
    _Pragma("unroll")                                                        \
    for (int m_ = 0; m_ < 12; ++m_) {                                        \
        cv2[2 * m_]     = sv_[m_].xy + tc2[2 * m_];                          \
        cv2[2 * m_ + 1] = sv_[m_].zw + tc2[2 * m_ + 1];                      \
    }                                                                        \
    cur = nxt_;                                                              \
} while (0)

__global__ __launch_bounds__(64, 1) void crf_viterbi(
    const float* __restrict__ pot,     // [B][T][C]
    const int*   __restrict__ seqlen,  // [B][1]
    const float* __restrict__ trans,   // [C][C]
    float*       __restrict__ out)     // [B][T][C] one-hot f32
{
    const int b   = blockIdx.x;
    const int tid = threadIdx.x;
    const int jj  = (tid < C_DIM) ? tid : (C_DIM - 1);  // clamped for safe loads

    __shared__ __align__(16) float sc[2][64];            // padded to 64 lanes
    __shared__ unsigned char bp[T_DIM * BPS];            // rows 1..L-1 used
    __shared__ __align__(4) unsigned char tags[T_DIM];

    const float* potb = pot + (size_t)b * (T_DIM * C_DIM);
    const int L   = seqlen[b];          // in [1, 511]
    const int thi = L - 1;

    // transitions column j as 24 packed pairs (clamped col for lanes >= 48)
    f32x2 tc2[24];
#pragma unroll
    for (int k = 0; k < 24; ++k) {
        tc2[k][0] = trans[(2 * k)     * C_DIM + jj];
        tc2[k][1] = trans[(2 * k + 1) * C_DIM + jj];
    }

    // init: stage scores s(0) = potentials[:,0] in LDS, compute cv2 for t=1
    sc[0][tid] = potb[jj];
    WAVE_SYNC();
    f32x2 cv2[24];
    {
        const f32x4* sp0 = (const f32x4*)sc[0];
#pragma unroll
        for (int m = 0; m < 12; ++m) {
            f32x4 sv = sp0[m];
            cv2[2 * m]     = sv.xy + tc2[2 * m];
            cv2[2 * m + 1] = sv.zw + tc2[2 * m + 1];
        }
    }
    int cur = 0;

    const float* pp = potb + jj;

    // software-pipelined forward loop: prefetch chunk CH ahead (clamped rows)
    float pb[CH];
#pragma unroll
    for (int k = 0; k < CH; ++k) {
        int tt = 1 + k; if (tt > T_DIM - 1) tt = T_DIM - 1;
        pb[k] = pp[tt * C_DIM];
    }
    for (int t0 = 1; t0 < L; t0 += CH) {
        float nb[CH];
#pragma unroll
        for (int k = 0; k < CH; ++k) {
            int tt = t0 + CH + k; if (tt > T_DIM - 1) tt = T_DIM - 1;
            nb[k] = pp[tt * C_DIM];
        }
#pragma unroll
        for (int k = 0; k < CH; ++k) {
            const int t = t0 + k;
            if (t >= L) break;           // wave-uniform branch
            VSTEP(t, pb[k]);
        }
#pragma unroll
        for (int k = 0; k < CH; ++k) pb[k] = nb[k];
    }
    __syncthreads();   // phase boundary (single wave; cheap)

    // last_tag = argmax over final scores (uniform LDS reads, broadcast)
    const float* fs = sc[cur];
    float bv = fs[0];
    int   bi = 0;
#pragma unroll
    for (int i = 1; i < C_DIM; ++i) {
        float v = fs[i];
        if (v > bv) { bv = v; bi = i; }
    }
    const int last_tag = __builtin_amdgcn_readfirstlane(bi);

    // prefill tags[t] = last_tag for t in [L, T)
    for (int t = L + tid; t < T_DIM; t += 64) tags[t] = (unsigned char)last_tag;

    // serial backtrace: for t = thi..1: tags[t] = y; y = bp[t][y];  then tags[0] = y
    int y = last_tag;  // wave-uniform
    for (int c0 = (thi >> 6) << 6; c0 >= 0; c0 -= 64) {
        int row[64];   // row[k] holds bp[c0+k][jj] in lane jj
#pragma unroll
        for (int k = 0; k < 64; ++k) row[k] = bp[(c0 + k) * BPS + jj];

        int vacc = 0;
#pragma unroll
        for (int k = 63; k >= 0; --k) {
            const int t = c0 + k;
            vacc = (tid == k) ? y : vacc;                        // tags[t] = y (lane k)
            const int ynew = READLANE_I(row[k], y);
            if ((unsigned)(t - 1) < (unsigned)thi) y = ynew;     // update only for t in [1, thi]
        }
        const int tk = c0 + tid;
        if (tk <= thi) tags[tk] = (unsigned char)(vacc & 0xff);
    }
    __syncthreads();   // phase boundary

    // emit one-hot: 4 rows (t) per iteration, 48 lanes x float4 = 768B coalesced
    if (tid < C_DIM) {
        const int r = tid / 12;          // row-in-group 0..3
        const int q = tid - r * 12;      // float4 slot 0..11
        const int cbase = q * 4;
        float* ob = out + (size_t)b * (T_DIM * C_DIM);
        for (int t0 = 0; t0 < T_DIM; t0 += 4) {
            const unsigned int tg4 = *(const unsigned int*)&tags[t0];
            const int mytag = (int)((tg4 >> (r * 8)) & 0xffu);
            float4 v;
            v.x = (cbase + 0 == mytag) ? 1.0f : 0.0f;
            v.y = (cbase + 1 == mytag) ? 1.0f : 0.0f;
            v.z = (cbase + 2 == mytag) ? 1.0f : 0.0f;
            v.w = (cbase + 3 == mytag) ? 1.0f : 0.0f;
            *(float4*)(ob + (size_t)(t0 + r) * C_DIM + cbase) = v;
        }
    }
}

extern "C" void kernel_launch(void* const* d_in, const int* in_sizes, int n_in,
                              void* d_out, int out_size, void* d_ws, size_t ws_size,
                              hipStream_t stream) {
    const float* pot    = (const float*)d_in[0];
    const int*   sl     = (const int*)d_in[1];
    const float* trans  = (const float*)d_in[2];
    float*       out    = (float*)d_out;
    const int B = in_sizes[1];  // sequence_lengths has B elements
    crf_viterbi<<<B, 64, 0, stream>>>(pot, sl, trans, out);
}